// Round 3
// baseline (9143.472 us; speedup 1.0000x reference)
//
#include <hip/hip_runtime.h>
#include <hip/hip_bf16.h>
#include <cstdint>
#include <cstddef>

// SwitchingRNN: B=64, T=512, I=256, L=512, K=8.  Output dtype: FLOAT32.
// Collapse experts first: h_t = WhhEff[b] @ h_{t-1} + X[b,t] + beff[b].
// X (f32) is materialized directly in d_out's states region and overwritten
// with h during the scan (same thread+address, read-before-write each step).

typedef _Float16 f16;
typedef _Float16 h2v __attribute__((ext_vector_type(2)));

#if defined(__has_builtin)
#if __has_builtin(__builtin_amdgcn_fdot2)
#define HAS_FDOT2 1
#endif
#endif

__device__ __forceinline__ float dot2f(unsigned a, unsigned b, float acc) {
#ifdef HAS_FDOT2
  union { unsigned u; h2v h; } ua, ub;
  ua.u = a; ub.u = b;
  return __builtin_amdgcn_fdot2(ua.h, ub.h, acc, false);
#else
  union { unsigned u; f16 f[2]; } ua, ub;
  ua.u = a; ub.u = b;
  acc += (float)ua.f[0] * (float)ub.f[0];
  acc += (float)ua.f[1] * (float)ub.f[1];
  return acc;
#endif
}

__device__ __forceinline__ float dot8(uint4 a, uint4 b, float acc) {
  acc = dot2f(a.x, b.x, acc);
  acc = dot2f(a.y, b.y, acc);
  acc = dot2f(a.z, b.z, acc);
  acc = dot2f(a.w, b.w, acc);
  return acc;
}

// ---- WhhEff[b][l][j] = sum_k p[b,k] * W_hh[k*512+l][j]  (f16 out)
__global__ __launch_bounds__(512) void mix_whh_kernel(
    const float* __restrict__ Whh, const float* __restrict__ p, f16* __restrict__ out) {
  __shared__ float ps[512];
  const int l = blockIdx.x, j = threadIdx.x;
  ps[j] = p[j];
  __syncthreads();
  float w[8];
#pragma unroll
  for (int k = 0; k < 8; ++k) w[k] = Whh[(size_t)(k * 512 + l) * 512 + j];
#pragma unroll 4
  for (int b = 0; b < 64; ++b) {
    float s = 0.f;
#pragma unroll
    for (int k = 0; k < 8; ++k) s += ps[b * 8 + k] * w[k];
    out[((size_t)(b * 512) + l) * 512 + j] = (f16)s;
  }
}

// ---- WihEff[b][l][j] = sum_k p[b,k] * W_ih[k*512+l][j]  (f16 out), j<256
__global__ __launch_bounds__(256) void mix_wih_kernel(
    const float* __restrict__ Wih, const float* __restrict__ p, f16* __restrict__ out) {
  __shared__ float ps[512];
  const int l = blockIdx.x, j = threadIdx.x;
  ps[j] = p[j];
  ps[j + 256] = p[j + 256];
  __syncthreads();
  float w[8];
#pragma unroll
  for (int k = 0; k < 8; ++k) w[k] = Wih[(size_t)(k * 512 + l) * 256 + j];
#pragma unroll 4
  for (int b = 0; b < 64; ++b) {
    float s = 0.f;
#pragma unroll
    for (int k = 0; k < 8; ++k) s += ps[b * 8 + k] * w[k];
    out[((size_t)(b * 512) + l) * 256 + j] = (f16)s;
  }
}

// ---- beff[b][l] = sum_k p[b,k]*(b_ih+b_hh+bias)[k*512+l]  (f32)
__global__ __launch_bounds__(512) void beff_kernel(
    const float* __restrict__ p, const float* __restrict__ b_ih,
    const float* __restrict__ b_hh, const float* __restrict__ bias,
    float* __restrict__ beff) {
  const int b = blockIdx.x, l = threadIdx.x;
  float s = 0.f;
#pragma unroll
  for (int k = 0; k < 8; ++k) {
    int o = k * 512 + l;
    s += p[b * 8 + k] * (b_ih[o] + b_hh[o] + bias[o]);
  }
  beff[b * 512 + l] = s;
}

// ---- X[b][t][l] = sum_i input[b,t,i] * WihEff[b][l][i]  -> f32 into d_out.
// 64x64 tile, K=256 in two 128-wide passes; 32 KB static LDS (XOR-swizzled).
__global__ __launch_bounds__(256) void xgemm_kernel(
    const float* __restrict__ inp, const f16* __restrict__ Wih,
    float* __restrict__ X) {
  __shared__ __align__(16) char sm[32768];  // A:[0,16K) 64r x 256B, B:[16K,32K)
  const int tid = threadIdx.x;
  const int t0 = blockIdx.x * 64, l0 = blockIdx.y * 64, b = blockIdx.z;
  const float* ib = inp + ((size_t)(b * 512 + t0)) * 256;
  const f16* wb = Wih + ((size_t)(b * 512 + l0)) * 256;
  const int ty = tid >> 4, tx = tid & 15;

  float acc[4][4];
#pragma unroll
  for (int a = 0; a < 4; ++a)
#pragma unroll
    for (int e = 0; e < 4; ++e) acc[a][e] = 0.f;

  for (int k2 = 0; k2 < 2; ++k2) {
    const int kb = k2 * 128;
    __syncthreads();
    // stage A (input -> f16, swizzled 16B chunks)
#pragma unroll
    for (int ph = 0; ph < 8; ++ph) {
      int s = tid + ph * 256;
      int t = s >> 5, q = s & 31;
      float4 v = *(const float4*)(ib + t * 256 + kb + q * 4);
      union { unsigned u; h2v h; } lo, hi;
      lo.h = h2v{(f16)v.x, (f16)v.y};
      hi.h = h2v{(f16)v.z, (f16)v.w};
      uint2 pk; pk.x = lo.u; pk.y = hi.u;
      int ch = q >> 1;
      *(uint2*)(sm + t * 256 + ((ch ^ (t & 15)) << 4) + (q & 1) * 8) = pk;
    }
    // stage B
#pragma unroll
    for (int ph = 0; ph < 4; ++ph) {
      int s = tid + ph * 256;
      int r = s >> 4, cc = s & 15;
      uint4 v = *(const uint4*)(wb + r * 256 + kb + cc * 8);
      *(uint4*)(sm + 16384 + r * 256 + ((cc ^ (r & 15)) << 4)) = v;
    }
    __syncthreads();
#pragma unroll 4
    for (int c = 0; c < 16; ++c) {
      uint4 iv[4], wv[4];
#pragma unroll
      for (int a = 0; a < 4; ++a) {
        int row = ty + a * 16;
        iv[a] = *(const uint4*)(sm + row * 256 + (((c ^ row) & 15) << 4));
      }
#pragma unroll
      for (int e = 0; e < 4; ++e) {
        int wr = tx + e * 16;
        wv[e] = *(const uint4*)(sm + 16384 + wr * 256 + (((c ^ wr) & 15) << 4));
      }
#pragma unroll
      for (int a = 0; a < 4; ++a)
#pragma unroll
        for (int e = 0; e < 4; ++e) acc[a][e] = dot8(iv[a], wv[e], acc[a][e]);
    }
  }
  float* xb = X + ((size_t)(b * 512 + t0)) * 512 + l0;
#pragma unroll
  for (int a = 0; a < 4; ++a)
#pragma unroll
    for (int e = 0; e < 4; ++e)
      xb[(ty + a * 16) * 512 + tx + e * 16] = acc[a][e];
}

// ---- persistent scan: 64 blocks x 512 threads (8 waves -> 256 VGPR cap).
// Thread (rg=tid>>4, cg=tid&15): rows rg*16+[0,16), cols cg*32+[0,32).
// Weights: rows 0..11 in regs (192 VGPRs), row12 + row13 ch0..2 in LDS (56KB),
// row13 ch3 + rows 14,15 streamed from L1/L2 each step (144 B/thread).
// h: f16 in 2x1KB XOR-swizzled LDS double buffer. After the packed shuffle
// tree, thread tid owns row tid -> coalesced f32 stores + X prefetch.
__global__ __launch_bounds__(512) void scan_kernel(
    const f16* __restrict__ Whh, const float* __restrict__ beff,
    const float* __restrict__ h0, float* __restrict__ out) {
  __shared__ uint4 wl[7 * 512];              // 57344 B
  __shared__ __align__(16) char hmem[2048];  // 2 x 1024 B h buffers

  const int tid = threadIdx.x;
  const int b = blockIdx.x;
  const int cg = tid & 15;
  const int rg = tid >> 4;

  const f16* wbase = Whh + ((size_t)(b * 512 + rg * 16)) * 512 + cg * 32;

  uint4 w[12][4];
#pragma unroll
  for (int r = 0; r < 12; ++r)
#pragma unroll
    for (int c = 0; c < 4; ++c)
      w[r][c] = *(const uint4*)(wbase + r * 512 + c * 8);

  // LDS classes: k=0..3 -> row12 chunk k; k=4..6 -> row13 chunk k-4
#pragma unroll
  for (int k = 0; k < 7; ++k) {
    int r = 12 + (k >> 2);
    int c = k & 3;
    wl[k * 512 + tid] = *(const uint4*)(wbase + r * 512 + c * 8);
  }

  // h0 -> buffer 0 (f16, swizzled: chunk m=row>>3, P = m ^ ((m>>2)&7))
  {
    float h0v = h0[b * 512 + tid];
    int m = tid >> 3;
    int P = m ^ ((m >> 2) & 7);
    *(f16*)(hmem + (P << 4) + (tid & 7) * 2) = (f16)h0v;
  }

  const float be = beff[b * 512 + tid];
  float* op = out + (size_t)b * 262144 + tid;
  float xv = op[0];  // X[b][0][tid] (xgemm ran earlier)

  const int wm = tid >> 3;
  const int hwoff = ((wm ^ ((wm >> 2) & 7)) << 4) + (tid & 7) * 2;
  int hroff[4];
#pragma unroll
  for (int c = 0; c < 4; ++c) {
    int m = cg * 4 + c;
    hroff[c] = (m ^ (cg & 7)) << 4;
  }

  const char* sbase = (const char*)(wbase + 13 * 512);  // stream base (row 13)

  __syncthreads();

  float hnew = 0.f;
#pragma unroll 2
  for (int t = 0; t < 512; ++t) {
    const int rb = (t & 1) ? 1024 : 0;
    const int wb2 = rb ^ 1024;

    // streamed weight chunks (L1/L2-resident after first iteration)
    uint4 s0 = *(const uint4*)(sbase + 48);    // row13 c3
    uint4 s1 = *(const uint4*)(sbase + 1024);  // row14 c0..3
    uint4 s2 = *(const uint4*)(sbase + 1040);
    uint4 s3 = *(const uint4*)(sbase + 1056);
    uint4 s4 = *(const uint4*)(sbase + 1072);
    uint4 s5 = *(const uint4*)(sbase + 2048);  // row15 c0..3
    uint4 s6 = *(const uint4*)(sbase + 2064);
    uint4 s7 = *(const uint4*)(sbase + 2080);
    uint4 s8 = *(const uint4*)(sbase + 2096);

    uint4 hv[4];
#pragma unroll
    for (int c = 0; c < 4; ++c)
      hv[c] = *(const uint4*)(hmem + rb + hroff[c]);

    float acc[16];
#pragma unroll
    for (int r = 0; r < 16; ++r) acc[r] = 0.f;

#pragma unroll
    for (int c = 0; c < 4; ++c) {
#pragma unroll
      for (int r = 0; r < 12; ++r) acc[r] = dot8(w[r][c], hv[c], acc[r]);
      acc[12] = dot8(wl[c * 512 + tid], hv[c], acc[12]);
      if (c < 3) acc[13] = dot8(wl[(4 + c) * 512 + tid], hv[c], acc[13]);
    }
    acc[13] = dot8(s0, hv[3], acc[13]);
    acc[14] = dot8(s1, hv[0], acc[14]);
    acc[14] = dot8(s2, hv[1], acc[14]);
    acc[14] = dot8(s3, hv[2], acc[14]);
    acc[14] = dot8(s4, hv[3], acc[14]);
    acc[15] = dot8(s5, hv[0], acc[15]);
    acc[15] = dot8(s6, hv[1], acc[15]);
    acc[15] = dot8(s7, hv[2], acc[15]);
    acc[15] = dot8(s8, hv[3], acc[15]);

    // packed tree reduction over the 16 cg lanes; ends with acc[0] = row tid
#pragma unroll
    for (int msk = 8; msk >= 1; msk >>= 1) {
      const bool up = (cg & msk) != 0;
#pragma unroll
      for (int j = 0; j < msk; ++j) {
        float snd = up ? acc[j] : acc[j + msk];
        float kp = up ? acc[j + msk] : acc[j];
        acc[j] = kp + __shfl_xor(snd, msk);
      }
    }

    hnew = acc[0] + xv + be;
    op[(size_t)t * 512] = hnew;
    *(f16*)(hmem + wb2 + hwoff) = (f16)hnew;
    int tn = (t < 511) ? t + 1 : 511;
    xv = op[(size_t)tn * 512];
    __syncthreads();
  }

  out[16777216 + b * 512 + tid] = hnew;
}

extern "C" void kernel_launch(void* const* d_in, const int* in_sizes, int n_in,
                              void* d_out, int out_size, void* d_ws, size_t ws_size,
                              hipStream_t stream) {
  (void)in_sizes; (void)n_in; (void)out_size; (void)ws_size;
  const float* input = (const float*)d_in[0];
  const float* h0    = (const float*)d_in[1];
  const float* p     = (const float*)d_in[2];
  const float* W_ih  = (const float*)d_in[3];
  const float* b_ih  = (const float*)d_in[4];
  const float* W_hh  = (const float*)d_in[5];
  const float* b_hh  = (const float*)d_in[6];
  const float* bias  = (const float*)d_in[7];
  float* out = (float*)d_out;

  char* ws = (char*)d_ws;
  f16* WhhE = (f16*)ws;                  // 64*512*512*2 = 33,554,432 B
  f16* WihE = (f16*)(ws + 33554432);     // 64*512*256*2 = 16,777,216 B
  float* be = (float*)(ws + 50331648);   // 64*512*4     =    131,072 B
  // total ws use: 50,462,720 B

  mix_whh_kernel<<<512, 512, 0, stream>>>(W_hh, p, WhhE);
  mix_wih_kernel<<<512, 256, 0, stream>>>(W_ih, p, WihE);
  beff_kernel<<<64, 512, 0, stream>>>(p, b_ih, b_hh, bias, be);
  xgemm_kernel<<<dim3(8, 8, 64), 256, 0, stream>>>(input, WihE, out);
  scan_kernel<<<64, 512, 0, stream>>>(WhhE, be, h0, out);
}

// Round 4
// 7983.720 us; speedup vs baseline: 1.1453x; 1.1453x over previous
//
#include <hip/hip_runtime.h>
#include <hip/hip_bf16.h>
#include <cstdint>
#include <cstddef>

// SwitchingRNN: B=64, T=512, I=256, L=512, K=8.  Output dtype: FLOAT32.
// Collapse experts first: h_t = WhhEff[b] @ h_{t-1} + X[b,t] + beff[b].
// X (f32) is materialized directly in d_out's states region and overwritten
// with h during the scan (same thread+address, read-before-write each step).

typedef _Float16 f16;
typedef _Float16 h2v __attribute__((ext_vector_type(2)));

#if defined(__has_builtin)
#if __has_builtin(__builtin_amdgcn_fdot2)
#define HAS_FDOT2 1
#endif
#if __has_builtin(__builtin_amdgcn_sched_barrier)
#define SCHED_FENCE() __builtin_amdgcn_sched_barrier(0)
#endif
#endif
#ifndef SCHED_FENCE
#define SCHED_FENCE()
#endif

__device__ __forceinline__ float dot2f(unsigned a, unsigned b, float acc) {
#ifdef HAS_FDOT2
  union { unsigned u; h2v h; } ua, ub;
  ua.u = a; ub.u = b;
  return __builtin_amdgcn_fdot2(ua.h, ub.h, acc, false);
#else
  union { unsigned u; f16 f[2]; } ua, ub;
  ua.u = a; ub.u = b;
  acc += (float)ua.f[0] * (float)ub.f[0];
  acc += (float)ua.f[1] * (float)ub.f[1];
  return acc;
#endif
}

__device__ __forceinline__ float dot8(uint4 a, uint4 b, float acc) {
  acc = dot2f(a.x, b.x, acc);
  acc = dot2f(a.y, b.y, acc);
  acc = dot2f(a.z, b.z, acc);
  acc = dot2f(a.w, b.w, acc);
  return acc;
}

// ---- WhhEff[b][l][j] = sum_k p[b,k] * W_hh[k*512+l][j]  (f16 out)
__global__ __launch_bounds__(512) void mix_whh_kernel(
    const float* __restrict__ Whh, const float* __restrict__ p, f16* __restrict__ out) {
  __shared__ float ps[512];
  const int l = blockIdx.x, j = threadIdx.x;
  ps[j] = p[j];
  __syncthreads();
  float w[8];
#pragma unroll
  for (int k = 0; k < 8; ++k) w[k] = Whh[(size_t)(k * 512 + l) * 512 + j];
#pragma unroll 4
  for (int b = 0; b < 64; ++b) {
    float s = 0.f;
#pragma unroll
    for (int k = 0; k < 8; ++k) s += ps[b * 8 + k] * w[k];
    out[((size_t)(b * 512) + l) * 512 + j] = (f16)s;
  }
}

// ---- WihEff[b][l][j] = sum_k p[b,k] * W_ih[k*512+l][j]  (f16 out), j<256
__global__ __launch_bounds__(256) void mix_wih_kernel(
    const float* __restrict__ Wih, const float* __restrict__ p, f16* __restrict__ out) {
  __shared__ float ps[512];
  const int l = blockIdx.x, j = threadIdx.x;
  ps[j] = p[j];
  ps[j + 256] = p[j + 256];
  __syncthreads();
  float w[8];
#pragma unroll
  for (int k = 0; k < 8; ++k) w[k] = Wih[(size_t)(k * 512 + l) * 256 + j];
#pragma unroll 4
  for (int b = 0; b < 64; ++b) {
    float s = 0.f;
#pragma unroll
    for (int k = 0; k < 8; ++k) s += ps[b * 8 + k] * w[k];
    out[((size_t)(b * 512) + l) * 256 + j] = (f16)s;
  }
}

// ---- beff[b][l] = sum_k p[b,k]*(b_ih+b_hh+bias)[k*512+l]  (f32)
__global__ __launch_bounds__(512) void beff_kernel(
    const float* __restrict__ p, const float* __restrict__ b_ih,
    const float* __restrict__ b_hh, const float* __restrict__ bias,
    float* __restrict__ beff) {
  const int b = blockIdx.x, l = threadIdx.x;
  float s = 0.f;
#pragma unroll
  for (int k = 0; k < 8; ++k) {
    int o = k * 512 + l;
    s += p[b * 8 + k] * (b_ih[o] + b_hh[o] + bias[o]);
  }
  beff[b * 512 + l] = s;
}

// ---- X[b][t][l] = sum_i input[b,t,i] * WihEff[b][l][i]  -> f32 into d_out.
// 64x64 tile, K=256 in two 128-wide passes; 32 KB static LDS (XOR-swizzled).
__global__ __launch_bounds__(256) void xgemm_kernel(
    const float* __restrict__ inp, const f16* __restrict__ Wih,
    float* __restrict__ X) {
  __shared__ __align__(16) char sm[32768];  // A:[0,16K) 64r x 256B, B:[16K,32K)
  const int tid = threadIdx.x;
  const int t0 = blockIdx.x * 64, l0 = blockIdx.y * 64, b = blockIdx.z;
  const float* ib = inp + ((size_t)(b * 512 + t0)) * 256;
  const f16* wb = Wih + ((size_t)(b * 512 + l0)) * 256;
  const int ty = tid >> 4, tx = tid & 15;

  float acc[4][4];
#pragma unroll
  for (int a = 0; a < 4; ++a)
#pragma unroll
    for (int e = 0; e < 4; ++e) acc[a][e] = 0.f;

  for (int k2 = 0; k2 < 2; ++k2) {
    const int kb = k2 * 128;
    __syncthreads();
    // stage A (input -> f16, swizzled 16B chunks)
#pragma unroll
    for (int ph = 0; ph < 8; ++ph) {
      int s = tid + ph * 256;
      int t = s >> 5, q = s & 31;
      float4 v = *(const float4*)(ib + t * 256 + kb + q * 4);
      union { unsigned u; h2v h; } lo, hi;
      lo.h = h2v{(f16)v.x, (f16)v.y};
      hi.h = h2v{(f16)v.z, (f16)v.w};
      uint2 pk; pk.x = lo.u; pk.y = hi.u;
      int ch = q >> 1;
      *(uint2*)(sm + t * 256 + ((ch ^ (t & 15)) << 4) + (q & 1) * 8) = pk;
    }
    // stage B
#pragma unroll
    for (int ph = 0; ph < 4; ++ph) {
      int s = tid + ph * 256;
      int r = s >> 4, cc = s & 15;
      uint4 v = *(const uint4*)(wb + r * 256 + kb + cc * 8);
      *(uint4*)(sm + 16384 + r * 256 + ((cc ^ (r & 15)) << 4)) = v;
    }
    __syncthreads();
#pragma unroll 4
    for (int c = 0; c < 16; ++c) {
      uint4 iv[4], wv[4];
#pragma unroll
      for (int a = 0; a < 4; ++a) {
        int row = ty + a * 16;
        iv[a] = *(const uint4*)(sm + row * 256 + (((c ^ row) & 15) << 4));
      }
#pragma unroll
      for (int e = 0; e < 4; ++e) {
        int wr = tx + e * 16;
        wv[e] = *(const uint4*)(sm + 16384 + wr * 256 + (((c ^ wr) & 15) << 4));
      }
#pragma unroll
      for (int a = 0; a < 4; ++a)
#pragma unroll
        for (int e = 0; e < 4; ++e) acc[a][e] = dot8(iv[a], wv[e], acc[a][e]);
    }
  }
  float* xb = X + ((size_t)(b * 512 + t0)) * 512 + l0;
#pragma unroll
  for (int a = 0; a < 4; ++a)
#pragma unroll
    for (int e = 0; e < 4; ++e)
      xb[(ty + a * 16) * 512 + tx + e * 16] = acc[a][e];
}

// ---- persistent scan: 64 blocks x 512 threads, 2 waves/EU -> 256 VGPR cap.
// Thread (rg=tid>>4, cg=tid&15): rows rg*16+[0,16), cols cg*32+[0,32).
// Weights: rows 0..10 in regs (176 VGPRs), rows 11 + 12(c0..2) in LDS (56KB),
// row12 c3 + rows 13..15 streamed from L2 each step (208 B/thread) in three
// batches fenced by sched_barrier(0) to bound register pressure.
// h: f16 in 2x1KB XOR-swizzled LDS double buffer. After the packed shuffle
// tree, thread tid owns row tid -> coalesced f32 stores + X prefetch.
__global__ __launch_bounds__(512, 2) void scan_kernel(
    const f16* __restrict__ Whh, const float* __restrict__ beff,
    const float* __restrict__ h0, float* __restrict__ out) {
  __shared__ uint4 wl[7 * 512];              // 57344 B
  __shared__ __align__(16) char hmem[2048];  // 2 x 1024 B h buffers

  const int tid = threadIdx.x;
  const int b = blockIdx.x;
  const int cg = tid & 15;
  const int rg = tid >> 4;

  const f16* wbase = Whh + ((size_t)(b * 512 + rg * 16)) * 512 + cg * 32;

  uint4 w[11][4];
#pragma unroll
  for (int r = 0; r < 11; ++r)
#pragma unroll
    for (int c = 0; c < 4; ++c)
      w[r][c] = *(const uint4*)(wbase + r * 512 + c * 8);

  // LDS classes: k=0..3 -> row11 chunk k; k=4..6 -> row12 chunk k-4
#pragma unroll
  for (int k = 0; k < 7; ++k) {
    int r = 11 + (k >> 2);
    int c = k & 3;
    wl[k * 512 + tid] = *(const uint4*)(wbase + r * 512 + c * 8);
  }

  // h0 -> buffer 0 (f16, swizzled: chunk m=row>>3, P = m ^ ((m>>2)&7))
  {
    float h0v = h0[b * 512 + tid];
    int m = tid >> 3;
    int P = m ^ ((m >> 2) & 7);
    *(f16*)(hmem + (P << 4) + (tid & 7) * 2) = (f16)h0v;
  }

  const float be = beff[b * 512 + tid];
  float* op = out + (size_t)b * 262144 + tid;
  float xv = op[0];  // X[b][0][tid] (xgemm ran earlier)

  const int wm = tid >> 3;
  const int hwoff = ((wm ^ ((wm >> 2) & 7)) << 4) + (tid & 7) * 2;
  int hroff[4];
#pragma unroll
  for (int c = 0; c < 4; ++c) {
    int m = cg * 4 + c;
    hroff[c] = (m ^ (cg & 7)) << 4;
  }

  const char* sbase = (const char*)(wbase + 12 * 512);  // stream base (row 12)

  __syncthreads();

  float hnew = 0.f;
#pragma unroll 2
  for (int t = 0; t < 512; ++t) {
    const int rb = (t & 1) ? 1024 : 0;
    const int wb2 = rb ^ 1024;

    uint4 hv[4];
#pragma unroll
    for (int c = 0; c < 4; ++c)
      hv[c] = *(const uint4*)(hmem + rb + hroff[c]);

    // batch A: row12 c3 + row13 c0..3 (L2-resident after first iteration)
    uint4 a0 = *(const uint4*)(sbase + 48);
    uint4 a1 = *(const uint4*)(sbase + 1024);
    uint4 a2 = *(const uint4*)(sbase + 1040);
    uint4 a3 = *(const uint4*)(sbase + 1056);
    uint4 a4 = *(const uint4*)(sbase + 1072);

    float acc[16];
#pragma unroll
    for (int r = 0; r < 16; ++r) acc[r] = 0.f;

    // register rows
#pragma unroll
    for (int c = 0; c < 4; ++c)
#pragma unroll
      for (int r = 0; r < 11; ++r) acc[r] = dot8(w[r][c], hv[c], acc[r]);
    // LDS rows
#pragma unroll
    for (int c = 0; c < 4; ++c) acc[11] = dot8(wl[c * 512 + tid], hv[c], acc[11]);
#pragma unroll
    for (int c = 0; c < 3; ++c) acc[12] = dot8(wl[(4 + c) * 512 + tid], hv[c], acc[12]);

    SCHED_FENCE();
    // batch B: row14
    uint4 b0 = *(const uint4*)(sbase + 2048);
    uint4 b1 = *(const uint4*)(sbase + 2064);
    uint4 b2 = *(const uint4*)(sbase + 2080);
    uint4 b3 = *(const uint4*)(sbase + 2096);
    // consume batch A
    acc[12] = dot8(a0, hv[3], acc[12]);
    acc[13] = dot8(a1, hv[0], acc[13]);
    acc[13] = dot8(a2, hv[1], acc[13]);
    acc[13] = dot8(a3, hv[2], acc[13]);
    acc[13] = dot8(a4, hv[3], acc[13]);

    SCHED_FENCE();
    // batch C: row15
    uint4 c0 = *(const uint4*)(sbase + 3072);
    uint4 c1 = *(const uint4*)(sbase + 3088);
    uint4 c2 = *(const uint4*)(sbase + 3104);
    uint4 c3 = *(const uint4*)(sbase + 3120);
    // consume batch B
    acc[14] = dot8(b0, hv[0], acc[14]);
    acc[14] = dot8(b1, hv[1], acc[14]);
    acc[14] = dot8(b2, hv[2], acc[14]);
    acc[14] = dot8(b3, hv[3], acc[14]);
    // consume batch C
    acc[15] = dot8(c0, hv[0], acc[15]);
    acc[15] = dot8(c1, hv[1], acc[15]);
    acc[15] = dot8(c2, hv[2], acc[15]);
    acc[15] = dot8(c3, hv[3], acc[15]);

    // packed tree reduction over the 16 cg lanes; ends with acc[0] = row tid
#pragma unroll
    for (int msk = 8; msk >= 1; msk >>= 1) {
      const bool up = (cg & msk) != 0;
#pragma unroll
      for (int j = 0; j < msk; ++j) {
        float snd = up ? acc[j] : acc[j + msk];
        float kp = up ? acc[j + msk] : acc[j];
        acc[j] = kp + __shfl_xor(snd, msk);
      }
    }

    hnew = acc[0] + xv + be;
    op[(size_t)t * 512] = hnew;
    *(f16*)(hmem + wb2 + hwoff) = (f16)hnew;
    int tn = (t < 511) ? t + 1 : 511;
    xv = op[(size_t)tn * 512];
    __syncthreads();
  }

  out[16777216 + b * 512 + tid] = hnew;
}

extern "C" void kernel_launch(void* const* d_in, const int* in_sizes, int n_in,
                              void* d_out, int out_size, void* d_ws, size_t ws_size,
                              hipStream_t stream) {
  (void)in_sizes; (void)n_in; (void)out_size; (void)ws_size;
  const float* input = (const float*)d_in[0];
  const float* h0    = (const float*)d_in[1];
  const float* p     = (const float*)d_in[2];
  const float* W_ih  = (const float*)d_in[3];
  const float* b_ih  = (const float*)d_in[4];
  const float* W_hh  = (const float*)d_in[5];
  const float* b_hh  = (const float*)d_in[6];
  const float* bias  = (const float*)d_in[7];
  float* out = (float*)d_out;

  char* ws = (char*)d_ws;
  f16* WhhE = (f16*)ws;                  // 64*512*512*2 = 33,554,432 B
  f16* WihE = (f16*)(ws + 33554432);     // 64*512*256*2 = 16,777,216 B
  float* be = (float*)(ws + 50331648);   // 64*512*4     =    131,072 B
  // total ws use: 50,462,720 B

  mix_whh_kernel<<<512, 512, 0, stream>>>(W_hh, p, WhhE);
  mix_wih_kernel<<<512, 256, 0, stream>>>(W_ih, p, WihE);
  beff_kernel<<<64, 512, 0, stream>>>(p, b_ih, b_hh, bias, be);
  xgemm_kernel<<<dim3(8, 8, 64), 256, 0, stream>>>(input, WihE, out);
  scan_kernel<<<64, 512, 0, stream>>>(WhhE, be, h0, out);
}

// Round 5
// 5160.505 us; speedup vs baseline: 1.7718x; 1.5471x over previous
//
#include <hip/hip_runtime.h>
#include <hip/hip_bf16.h>
#include <cstdint>
#include <cstddef>

// SwitchingRNN: B=64, T=512, I=256, L=512, K=8.  Output dtype: FLOAT32.
// Collapse experts first: h_t = WhhEff[b] @ h_{t-1} + X[b,t] + beff[b].
// X (f32) is materialized directly in d_out's states region and overwritten
// with h during the scan (same thread+address, read-before-write each step).

typedef _Float16 f16;
typedef _Float16 h2v __attribute__((ext_vector_type(2)));

#if defined(__has_builtin)
#if __has_builtin(__builtin_amdgcn_fdot2)
#define HAS_FDOT2 1
#endif
#if __has_builtin(__builtin_amdgcn_sched_barrier)
#define SCHED_FENCE() __builtin_amdgcn_sched_barrier(0)
#endif
#endif
#ifndef SCHED_FENCE
#define SCHED_FENCE()
#endif

#if defined(__has_attribute)
#if __has_attribute(amdgpu_waves_per_eu)
#define WAVES22 __attribute__((amdgpu_waves_per_eu(2, 2)))
#endif
#endif
#ifndef WAVES22
#define WAVES22
#endif

__device__ __forceinline__ float dot2f(unsigned a, unsigned b, float acc) {
#ifdef HAS_FDOT2
  union { unsigned u; h2v h; } ua, ub;
  ua.u = a; ub.u = b;
  return __builtin_amdgcn_fdot2(ua.h, ub.h, acc, false);
#else
  union { unsigned u; f16 f[2]; } ua, ub;
  ua.u = a; ub.u = b;
  acc += (float)ua.f[0] * (float)ub.f[0];
  acc += (float)ua.f[1] * (float)ub.f[1];
  return acc;
#endif
}

__device__ __forceinline__ float dot8(uint4 a, uint4 b, float acc) {
  acc = dot2f(a.x, b.x, acc);
  acc = dot2f(a.y, b.y, acc);
  acc = dot2f(a.z, b.z, acc);
  acc = dot2f(a.w, b.w, acc);
  return acc;
}

// ---- WhhEff[b][l][j] = sum_k p[b,k] * W_hh[k*512+l][j]  (f16 out)
__global__ __launch_bounds__(512) void mix_whh_kernel(
    const float* __restrict__ Whh, const float* __restrict__ p, f16* __restrict__ out) {
  __shared__ float ps[512];
  const int l = blockIdx.x, j = threadIdx.x;
  ps[j] = p[j];
  __syncthreads();
  float w[8];
#pragma unroll
  for (int k = 0; k < 8; ++k) w[k] = Whh[(size_t)(k * 512 + l) * 512 + j];
#pragma unroll 4
  for (int b = 0; b < 64; ++b) {
    float s = 0.f;
#pragma unroll
    for (int k = 0; k < 8; ++k) s += ps[b * 8 + k] * w[k];
    out[((size_t)(b * 512) + l) * 512 + j] = (f16)s;
  }
}

// ---- WihEff[b][l][j] = sum_k p[b,k] * W_ih[k*512+l][j]  (f16 out), j<256
__global__ __launch_bounds__(256) void mix_wih_kernel(
    const float* __restrict__ Wih, const float* __restrict__ p, f16* __restrict__ out) {
  __shared__ float ps[512];
  const int l = blockIdx.x, j = threadIdx.x;
  ps[j] = p[j];
  ps[j + 256] = p[j + 256];
  __syncthreads();
  float w[8];
#pragma unroll
  for (int k = 0; k < 8; ++k) w[k] = Wih[(size_t)(k * 512 + l) * 256 + j];
#pragma unroll 4
  for (int b = 0; b < 64; ++b) {
    float s = 0.f;
#pragma unroll
    for (int k = 0; k < 8; ++k) s += ps[b * 8 + k] * w[k];
    out[((size_t)(b * 512) + l) * 256 + j] = (f16)s;
  }
}

// ---- beff[b][l] = sum_k p[b,k]*(b_ih+b_hh+bias)[k*512+l]  (f32)
__global__ __launch_bounds__(512) void beff_kernel(
    const float* __restrict__ p, const float* __restrict__ b_ih,
    const float* __restrict__ b_hh, const float* __restrict__ bias,
    float* __restrict__ beff) {
  const int b = blockIdx.x, l = threadIdx.x;
  float s = 0.f;
#pragma unroll
  for (int k = 0; k < 8; ++k) {
    int o = k * 512 + l;
    s += p[b * 8 + k] * (b_ih[o] + b_hh[o] + bias[o]);
  }
  beff[b * 512 + l] = s;
}

// ---- X[b][t][l] = sum_i input[b,t,i] * WihEff[b][l][i]  -> f32 into d_out.
// 64x64 tile, K=256 in two 128-wide passes; 32 KB static LDS (XOR-swizzled).
__global__ __launch_bounds__(256) void xgemm_kernel(
    const float* __restrict__ inp, const f16* __restrict__ Wih,
    float* __restrict__ X) {
  __shared__ __align__(16) char sm[32768];  // A:[0,16K) 64r x 256B, B:[16K,32K)
  const int tid = threadIdx.x;
  const int t0 = blockIdx.x * 64, l0 = blockIdx.y * 64, b = blockIdx.z;
  const float* ib = inp + ((size_t)(b * 512 + t0)) * 256;
  const f16* wb = Wih + ((size_t)(b * 512 + l0)) * 256;
  const int ty = tid >> 4, tx = tid & 15;

  float acc[4][4];
#pragma unroll
  for (int a = 0; a < 4; ++a)
#pragma unroll
    for (int e = 0; e < 4; ++e) acc[a][e] = 0.f;

  for (int k2 = 0; k2 < 2; ++k2) {
    const int kb = k2 * 128;
    __syncthreads();
    // stage A (input -> f16, swizzled 16B chunks)
#pragma unroll
    for (int ph = 0; ph < 8; ++ph) {
      int s = tid + ph * 256;
      int t = s >> 5, q = s & 31;
      float4 v = *(const float4*)(ib + t * 256 + kb + q * 4);
      union { unsigned u; h2v h; } lo, hi;
      lo.h = h2v{(f16)v.x, (f16)v.y};
      hi.h = h2v{(f16)v.z, (f16)v.w};
      uint2 pk; pk.x = lo.u; pk.y = hi.u;
      int ch = q >> 1;
      *(uint2*)(sm + t * 256 + ((ch ^ (t & 15)) << 4) + (q & 1) * 8) = pk;
    }
    // stage B
#pragma unroll
    for (int ph = 0; ph < 4; ++ph) {
      int s = tid + ph * 256;
      int r = s >> 4, cc = s & 15;
      uint4 v = *(const uint4*)(wb + r * 256 + kb + cc * 8);
      *(uint4*)(sm + 16384 + r * 256 + ((cc ^ (r & 15)) << 4)) = v;
    }
    __syncthreads();
#pragma unroll 4
    for (int c = 0; c < 16; ++c) {
      uint4 iv[4], wv[4];
#pragma unroll
      for (int a = 0; a < 4; ++a) {
        int row = ty + a * 16;
        iv[a] = *(const uint4*)(sm + row * 256 + (((c ^ row) & 15) << 4));
      }
#pragma unroll
      for (int e = 0; e < 4; ++e) {
        int wr = tx + e * 16;
        wv[e] = *(const uint4*)(sm + 16384 + wr * 256 + (((c ^ wr) & 15) << 4));
      }
#pragma unroll
      for (int a = 0; a < 4; ++a)
#pragma unroll
        for (int e = 0; e < 4; ++e) acc[a][e] = dot8(iv[a], wv[e], acc[a][e]);
    }
  }
  float* xb = X + ((size_t)(b * 512 + t0)) * 512 + l0;
#pragma unroll
  for (int a = 0; a < 4; ++a)
#pragma unroll
    for (int e = 0; e < 4; ++e)
      xb[(ty + a * 16) * 512 + tx + e * 16] = acc[a][e];
}

// ---- persistent scan: 64 blocks x 512 threads, waves_per_eu(2,2) -> 256 VGPRs.
// Thread (rg=tid>>4, cg=tid&15): rows rg*16+[0,16), cols cg*32+[0,32).
// Weights: rows 0..7 in regs (128 VGPRs), rows 8 + 9(c0..2) in LDS (56KB),
// row9c3 + rows 10..15 streamed from L2 (25 x 16B chunks/thread/step),
// software-pipelined per chunk-column c: stage c prefetches stage c+1's
// global chunks, LDS weight rows, and h chunk; stage 3 prefetches next
// step's c0 data (weights are t-invariant, legal across the barrier).
__global__ void __launch_bounds__(512) WAVES22 scan_kernel(
    const f16* __restrict__ Whh, const float* __restrict__ beff,
    const float* __restrict__ h0, float* __restrict__ out) {
  __shared__ uint4 wl[7 * 512];              // 57344 B
  __shared__ __align__(16) char hmem[2048];  // 2 x 1024 B h buffers

  const int tid = threadIdx.x;
  const int b = blockIdx.x;
  const int cg = tid & 15;
  const int rg = tid >> 4;

  const f16* wbase = Whh + ((size_t)(b * 512 + rg * 16)) * 512 + cg * 32;

  uint4 w[8][4];
#pragma unroll
  for (int r = 0; r < 8; ++r)
#pragma unroll
    for (int c = 0; c < 4; ++c)
      w[r][c] = *(const uint4*)(wbase + r * 512 + c * 8);

  // LDS classes: k=0..3 -> row8 chunk k; k=4..6 -> row9 chunk k-4
#pragma unroll
  for (int k = 0; k < 7; ++k) {
    int r = 8 + (k >> 2);
    int c = k & 3;
    wl[k * 512 + tid] = *(const uint4*)(wbase + r * 512 + c * 8);
  }

  // h0 -> buffer 0 (f16, swizzled: chunk m=row>>3, P = m ^ ((m>>2)&7))
  {
    float h0v = h0[b * 512 + tid];
    int m = tid >> 3;
    int P = m ^ ((m >> 2) & 7);
    *(f16*)(hmem + (P << 4) + (tid & 7) * 2) = (f16)h0v;
  }

  const float be = beff[b * 512 + tid];
  float* opc = out + (size_t)b * 262144 + tid;
  float xv = opc[0];  // X[b][0][tid]

  const int wm = tid >> 3;
  const int hwoff = ((wm ^ ((wm >> 2) & 7)) << 4) + (tid & 7) * 2;
  const char* hvaddr[4];
#pragma unroll
  for (int c = 0; c < 4; ++c) {
    int m = cg * 4 + c;
    hvaddr[c] = hmem + ((m ^ (cg & 7)) << 4);
  }

  const char* sb9 = (const char*)(wbase + 9 * 512);  // row9 byte base
  const char* sb13 = sb9 + 4096;                     // row13 byte base

  __syncthreads();

#define LD(p) (*(const uint4*)(p))

  // prologue: buffer A <- c0 chunks; LDS classes k0,k4
  uint4 ga0 = LD(sb9 + 1024);         // row10 c0
  uint4 ga1 = LD(sb9 + 2048);         // row11 c0
  uint4 ga2 = LD(sb9 + 3072);         // row12 c0
  uint4 ga3 = LD(sb13);               // row13 c0
  uint4 ga4 = LD(sb13 + 1024);        // row14 c0
  uint4 ga5 = LD(sb13 + 2048);        // row15 c0
  uint4 gb0, gb1, gb2, gb3, gb4, gb5, gb6;
  uint4 wl8a = wl[0 * 512 + tid];
  uint4 wl9a = wl[4 * 512 + tid];
  uint4 wl8b, wl9b, hva, hvb;
  float hnew = 0.f;

#define STAGE_DOTS(ci, HV, WL8V, R9V, G0, G1, G2, G3, G4, G5)            \
  {                                                                      \
    _Pragma("unroll") for (int r = 0; r < 8; ++r)                        \
        acc[r] = dot8(w[r][ci], HV, acc[r]);                             \
    acc[8] = dot8(WL8V, HV, acc[8]);                                     \
    acc[9] = dot8(R9V, HV, acc[9]);                                      \
    acc[10] = dot8(G0, HV, acc[10]);                                     \
    acc[11] = dot8(G1, HV, acc[11]);                                     \
    acc[12] = dot8(G2, HV, acc[12]);                                     \
    acc[13] = dot8(G3, HV, acc[13]);                                     \
    acc[14] = dot8(G4, HV, acc[14]);                                     \
    acc[15] = dot8(G5, HV, acc[15]);                                     \
  }

#define STEP(RB, WB)                                                     \
  {                                                                      \
    float acc[16];                                                       \
    _Pragma("unroll") for (int r = 0; r < 16; ++r) acc[r] = 0.f;         \
    hva = LD(hvaddr[0] + (RB));                                          \
    /* stage 0: prefetch c1 */                                           \
    gb0 = LD(sb9 + 1024 + 16); gb1 = LD(sb9 + 2048 + 16);                \
    gb2 = LD(sb9 + 3072 + 16); gb3 = LD(sb13 + 16);                      \
    gb4 = LD(sb13 + 1024 + 16); gb5 = LD(sb13 + 2048 + 16);              \
    wl8b = wl[1 * 512 + tid]; wl9b = wl[5 * 512 + tid];                  \
    hvb = LD(hvaddr[1] + (RB));                                          \
    STAGE_DOTS(0, hva, wl8a, wl9a, ga0, ga1, ga2, ga3, ga4, ga5)         \
    SCHED_FENCE();                                                       \
    /* stage 1: prefetch c2 */                                           \
    ga0 = LD(sb9 + 1024 + 32); ga1 = LD(sb9 + 2048 + 32);                \
    ga2 = LD(sb9 + 3072 + 32); ga3 = LD(sb13 + 32);                      \
    ga4 = LD(sb13 + 1024 + 32); ga5 = LD(sb13 + 2048 + 32);              \
    wl8a = wl[2 * 512 + tid]; wl9a = wl[6 * 512 + tid];                  \
    hva = LD(hvaddr[2] + (RB));                                          \
    STAGE_DOTS(1, hvb, wl8b, wl9b, gb0, gb1, gb2, gb3, gb4, gb5)         \
    SCHED_FENCE();                                                       \
    /* stage 2: prefetch c3 (incl row9c3) */                             \
    gb0 = LD(sb9 + 1024 + 48); gb1 = LD(sb9 + 2048 + 48);                \
    gb2 = LD(sb9 + 3072 + 48); gb3 = LD(sb13 + 48);                      \
    gb4 = LD(sb13 + 1024 + 48); gb5 = LD(sb13 + 2048 + 48);              \
    gb6 = LD(sb9 + 48);                                                  \
    wl8b = wl[3 * 512 + tid];                                            \
    hvb = LD(hvaddr[3] + (RB));                                          \
    STAGE_DOTS(2, hva, wl8a, wl9a, ga0, ga1, ga2, ga3, ga4, ga5)         \
    SCHED_FENCE();                                                       \
    /* stage 3: prefetch next step's c0 (weights, t-invariant) */        \
    ga0 = LD(sb9 + 1024); ga1 = LD(sb9 + 2048);                          \
    ga2 = LD(sb9 + 3072); ga3 = LD(sb13);                                \
    ga4 = LD(sb13 + 1024); ga5 = LD(sb13 + 2048);                        \
    wl8a = wl[0 * 512 + tid]; wl9a = wl[4 * 512 + tid];                  \
    STAGE_DOTS(3, hvb, wl8b, gb6, gb0, gb1, gb2, gb3, gb4, gb5)          \
    SCHED_FENCE();                                                       \
    /* packed tree over the 16 cg lanes -> acc[0] = row tid */           \
    _Pragma("unroll") for (int msk = 8; msk >= 1; msk >>= 1) {           \
      const bool up = (cg & msk) != 0;                                   \
      _Pragma("unroll") for (int j = 0; j < msk; ++j) {                  \
        float snd = up ? acc[j] : acc[j + msk];                          \
        float kp = up ? acc[j + msk] : acc[j];                           \
        acc[j] = kp + __shfl_xor(snd, msk);                              \
      }                                                                  \
    }                                                                    \
    hnew = acc[0] + xv + be;                                             \
    opc[0] = hnew;                                                       \
    *(f16*)(hmem + (WB) + hwoff) = (f16)hnew;                            \
    xv = opc[512];                                                       \
    opc += 512;                                                          \
    __syncthreads();                                                     \
  }

  for (int t = 0; t < 512; t += 2) {
    STEP(0, 1024)
    STEP(1024, 0)
  }
#undef STEP
#undef STAGE_DOTS
#undef LD

  out[16777216 + b * 512 + tid] = hnew;
}

extern "C" void kernel_launch(void* const* d_in, const int* in_sizes, int n_in,
                              void* d_out, int out_size, void* d_ws, size_t ws_size,
                              hipStream_t stream) {
  (void)in_sizes; (void)n_in; (void)out_size; (void)ws_size;
  const float* input = (const float*)d_in[0];
  const float* h0    = (const float*)d_in[1];
  const float* p     = (const float*)d_in[2];
  const float* W_ih  = (const float*)d_in[3];
  const float* b_ih  = (const float*)d_in[4];
  const float* W_hh  = (const float*)d_in[5];
  const float* b_hh  = (const float*)d_in[6];
  const float* bias  = (const float*)d_in[7];
  float* out = (float*)d_out;

  char* ws = (char*)d_ws;
  f16* WhhE = (f16*)ws;                  // 64*512*512*2 = 33,554,432 B
  f16* WihE = (f16*)(ws + 33554432);     // 64*512*256*2 = 16,777,216 B
  float* be = (float*)(ws + 50331648);   // 64*512*4     =    131,072 B
  // total ws use: 50,462,720 B

  mix_whh_kernel<<<512, 512, 0, stream>>>(W_hh, p, WhhE);
  mix_wih_kernel<<<512, 256, 0, stream>>>(W_ih, p, WihE);
  beff_kernel<<<64, 512, 0, stream>>>(p, b_ih, b_hh, bias, be);
  xgemm_kernel<<<dim3(8, 8, 64), 256, 0, stream>>>(input, WihE, out);
  scan_kernel<<<64, 512, 0, stream>>>(WhhE, be, h0, out);
}